// Round 3
// baseline (336.998 us; speedup 1.0000x reference)
//
#include <hip/hip_runtime.h>

typedef unsigned short u16;
typedef unsigned int   u32;
typedef _Float16 f16x8 __attribute__((ext_vector_type(8)));
typedef u32    u32x4 __attribute__((ext_vector_type(4)));
typedef float  f32x4 __attribute__((ext_vector_type(4)));

#define NEG_BIG (-3.4028234663852886e38f)
#define LO_SCALE 2048.0f
#define LO_INV   (1.0f/2048.0f)

__device__ __forceinline__ u32 splitpack(float x){
  _Float16 h = (_Float16)x;                       // RTNE
  _Float16 l = (_Float16)((x - (float)h) * LO_SCALE);
  return (u32)__builtin_bit_cast(u16, h) | ((u32)__builtin_bit_cast(u16, l) << 16);
}
__device__ __forceinline__ void split2(float x, _Float16& h, _Float16& l){
  h = (_Float16)x;
  l = (_Float16)((x - (float)h) * LO_SCALE);
}
__device__ __forceinline__ void unpack8(const u32* p, f16x8& h, f16x8& l){
  #pragma unroll
  for (int j = 0; j < 8; j++){
    u32 v = p[j];
    h[j] = __builtin_bit_cast(_Float16, (u16)(v & 0xFFFFu));
    l[j] = __builtin_bit_cast(_Float16, (u16)(v >> 16));
  }
}
__device__ __forceinline__ float wsum(float v){
  #pragma unroll
  for (int m = 32; m >= 1; m >>= 1) v += __shfl_xor(v, m, 64);
  return v;
}
__device__ __forceinline__ float wmax(float v){
  #pragma unroll
  for (int m = 32; m >= 1; m >>= 1) v = fmaxf(v, __shfl_xor(v, m, 64));
  return v;
}

// ---------------------------------------------------------------------------
// K0: LN(inputs); [k|v] = xn @ [Wk|Wv] via split-f16 3-term MFMA (fp32-class
// accuracy). kws: [b][s][d] packed u32 (f16 hi | lo<<16). vws: [b][d][s] same.
// Block 256 thr / 64 rows / 128 cols; wave w owns cols [32w,32w+32).
// ---------------------------------------------------------------------------
__global__ __launch_bounds__(256, 2)
void k_proj(const float* __restrict__ in, const float* __restrict__ g,
            const float* __restrict__ bb, const float* __restrict__ Wk,
            const float* __restrict__ Wv, u32* __restrict__ kws,
            u32* __restrict__ vws)
{
  __shared__ u32 A[64 * 258];   // 66 KB; reused as 64x130 u32 output stage
  const int t = threadIdx.x, w = t >> 6, l = t & 63, q = l >> 4, l15 = l & 15;
  const long base = (long)blockIdx.x * 64;

  // prefetch rows (wave w owns row 4i+w)
  f32x4 xv[16];
  const f32x4* in4 = (const f32x4*)in;
  #pragma unroll
  for (int i = 0; i < 16; i++) xv[i] = in4[(base + i*4 + w) * 64 + l];

  const f32x4 gv = ((const f32x4*)g)[l];
  const f32x4 bv = ((const f32x4*)bb)[l];

  // LN + split-pack to LDS (u32 per element, row stride 258)
  #pragma unroll
  for (int i = 0; i < 16; i++){
    f32x4 x = xv[i];
    float s  = x.x + x.y + x.z + x.w;
    float ss = x.x*x.x + x.y*x.y + x.z*x.z + x.w*x.w;
    s = wsum(s); ss = wsum(ss);
    float mean = s * (1.f/256.f);
    float var  = fmaxf(ss * (1.f/256.f) - mean*mean, 0.f);
    float rstd = rsqrtf(var + 1e-5f);
    int row = i*4 + w;
    u32x4 o;
    o[0] = splitpack((x.x - mean) * rstd * gv.x + bv.x);
    o[1] = splitpack((x.y - mean) * rstd * gv.y + bv.y);
    o[2] = splitpack((x.z - mean) * rstd * gv.z + bv.z);
    o[3] = splitpack((x.w - mean) * rstd * gv.w + bv.w);
    *(u32x4*)&A[row*258 + l*4] = o;
  }
  __syncthreads();

  f32x4 a1[4][2] = {};   // hi*hi accumulator
  f32x4 a2[4][2] = {};   // (hi*lo' + lo'*hi) accumulator, scale 2048x

  #pragma unroll
  for (int half = 0; half < 2; half++){
    // B fragments for kt in [4*half, 4*half+4)
    f16x8 bh[2][4], bl[2][4];
    #pragma unroll
    for (int n2 = 0; n2 < 2; n2++){
      const int n = w*32 + n2*16 + l15;
      const float* src = (n < 64) ? (Wk + n) : (Wv + (n - 64));
      #pragma unroll
      for (int k4 = 0; k4 < 4; k4++){
        #pragma unroll
        for (int j = 0; j < 8; j++){
          float wv = src[((half*4 + k4)*32 + q*8 + j) * 64];
          _Float16 h, lo; split2(wv, h, lo);
          bh[n2][k4][j] = h; bl[n2][k4][j] = lo;
        }
      }
    }
    #pragma unroll
    for (int k4 = 0; k4 < 4; k4++){
      const int kt = half*4 + k4;
      f16x8 ah[4], al[4];
      #pragma unroll
      for (int mt = 0; mt < 4; mt++)
        unpack8(&A[(mt*16 + l15)*258 + kt*32 + q*8], ah[mt], al[mt]);
      #pragma unroll
      for (int mt = 0; mt < 4; mt++)
        #pragma unroll
        for (int n2 = 0; n2 < 2; n2++){
          a1[mt][n2] = __builtin_amdgcn_mfma_f32_16x16x32_f16(ah[mt], bh[n2][k4], a1[mt][n2], 0,0,0);
          a2[mt][n2] = __builtin_amdgcn_mfma_f32_16x16x32_f16(ah[mt], bl[n2][k4], a2[mt][n2], 0,0,0);
          a2[mt][n2] = __builtin_amdgcn_mfma_f32_16x16x32_f16(al[mt], bh[n2][k4], a2[mt][n2], 0,0,0);
        }
    }
  }
  __syncthreads();

  // stage C tile (packed u32) for coalesced global writes
  #pragma unroll
  for (int mt = 0; mt < 4; mt++)
    #pragma unroll
    for (int n2 = 0; n2 < 2; n2++)
      #pragma unroll
      for (int r = 0; r < 4; r++){
        int row = mt*16 + q*4 + r;
        int col = w*32 + n2*16 + l15;          // 0..63 k, 64..127 v
        A[row*130 + col] = splitpack(a1[mt][n2][r] + a2[mt][n2][r] * LO_INV);
      }
  __syncthreads();

  const int b  = (int)(base >> 12);
  const int s0 = (int)(base & 4095);
  // k half: [b][s][d] contiguous, 64 rows x 16 segs of 4 u32
  for (int task = t; task < 1024; task += 256){
    int row = task >> 4, seg = task & 15;
    u32x4 val = *(const u32x4*)&A[row*130 + seg*4];
    *(u32x4*)(kws + ((long)b*4096 + s0 + row)*64 + seg*4) = val;
  }
  // v half transposed: [b][d][s]
  for (int task = t; task < 1024; task += 256){
    int d = task >> 4, seg = task & 15;
    u32x4 vv;
    #pragma unroll
    for (int j = 0; j < 4; j++) vv[j] = A[(seg*4 + j)*130 + 64 + d];
    *(u32x4*)(vws + ((long)b*64 + d)*4096 + s0 + seg*4) = vv;
  }
}

// ---------------------------------------------------------------------------
// per-(b, s-chunk of 256): scores via split-f16 MFMA, chunk softmax stats,
// PV partial via split-f16 MFMA. Persists masked+scaled fp32 scores.
// ---------------------------------------------------------------------------
__global__ __launch_bounds__(256)
void k_attn_part(const float* __restrict__ qws, const u32* __restrict__ kws,
                 const u32* __restrict__ vws, const int* __restrict__ mask,
                 float* __restrict__ scores, float* __restrict__ part)
{
  __shared__ float pl[8 * 256];
  __shared__ u32   pb[16 * 258];
  __shared__ float ml[8];
  const int c = blockIdx.x, b = blockIdx.y;
  const int t = threadIdx.x, w = t >> 6, l = t & 63, q = l >> 4, l15 = l & 15;

  // --- phase 1: scores = K_chunk(256x64) @ Q^T ; wave w -> s in [64w,64w+64)
  f16x8 qh[2], ql[2];
  #pragma unroll
  for (int kt = 0; kt < 2; kt++){
    #pragma unroll
    for (int j = 0; j < 8; j++){
      int d = kt*32 + q*8 + j;
      float qv = (l15 < 8) ? qws[b*512 + l15*64 + d] : 0.f;
      _Float16 h, lo; split2(qv, h, lo);
      qh[kt][j] = h; ql[kt][j] = lo;
    }
  }
  f32x4 s1[4] = {}, s2[4] = {};
  #pragma unroll
  for (int kt = 0; kt < 2; kt++)
    #pragma unroll
    for (int mt = 0; mt < 4; mt++){
      const u32* kr = kws + ((long)b*4096 + c*256 + w*64 + mt*16 + l15)*64
                      + kt*32 + q*8;
      f16x8 ah, al; unpack8(kr, ah, al);
      s1[mt] = __builtin_amdgcn_mfma_f32_16x16x32_f16(ah, qh[kt], s1[mt], 0,0,0);
      s2[mt] = __builtin_amdgcn_mfma_f32_16x16x32_f16(ah, ql[kt], s2[mt], 0,0,0);
      s2[mt] = __builtin_amdgcn_mfma_f32_16x16x32_f16(al, qh[kt], s2[mt], 0,0,0);
    }
  #pragma unroll
  for (int mt = 0; mt < 4; mt++)
    #pragma unroll
    for (int r = 0; r < 4; r++)
      if (l15 < 8)
        pl[l15*256 + w*64 + mt*16 + q*4 + r] = s1[mt][r] + s2[mt][r] * LO_INV;
  __syncthreads();

  // --- phase 2: scale + mask, persist scores; thread t <-> s = c*256+t
  const int s = c*256 + t;
  const int mk = mask[b*4096 + s];
  float sc[8];
  #pragma unroll
  for (int k8 = 0; k8 < 8; k8++){
    float v0 = pl[k8*256 + t] * 0.125f;
    sc[k8] = mk ? v0 : NEG_BIG;
    scores[((long)(b*8 + k8))*4096 + s] = sc[k8];
    pl[k8*256 + t] = sc[k8];
  }
  __syncthreads();

  // --- phase 3: chunk max per slot
  #pragma unroll
  for (int i = 0; i < 2; i++){
    int slot = w*2 + i;
    float m = fmaxf(fmaxf(pl[slot*256 + l],       pl[slot*256 + 64 + l]),
                    fmaxf(pl[slot*256 + 128 + l], pl[slot*256 + 192 + l]));
    m = wmax(m);
    if (l == 0) ml[slot] = m;
  }
  __syncthreads();

  // --- phase 4: p = exp(sc - m); fp32 in pl, split-packed in pb
  #pragma unroll
  for (int k8 = 0; k8 < 8; k8++){
    float p = mk ? expf(sc[k8] - ml[k8]) : 0.f;
    pl[k8*256 + t] = p;
    pb[k8*258 + t] = splitpack(p);
  }
  #pragma unroll
  for (int k8 = 8; k8 < 16; k8++) pb[k8*258 + t] = 0;
  __syncthreads();

  // --- phase 5: chunk exp-sums -> (m, l) partials
  #pragma unroll
  for (int i = 0; i < 2; i++){
    int slot = w*2 + i;
    float sm = pl[slot*256 + l] + pl[slot*256 + 64 + l]
             + pl[slot*256 + 128 + l] + pl[slot*256 + 192 + l];
    sm = wsum(sm);
    if (l == 0){
      float* pp = part + ((long)(b*16 + c)*8 + slot)*66;
      pp[0] = ml[slot]; pp[1] = sm;
    }
  }

  // --- phase 6: o_partial = P(16pad x 256) @ V(256 x 64); wave w -> d-tile w
  f32x4 o1 = {}, o2 = {};
  #pragma unroll
  for (int kt = 0; kt < 8; kt++){
    f16x8 ph, plo; unpack8(&pb[l15*258 + kt*32 + q*8], ph, plo);
    const u32* vr = vws + ((long)b*64 + w*16 + l15)*4096 + c*256 + kt*32 + q*8;
    f16x8 vh, vl; unpack8(vr, vh, vl);
    o1 = __builtin_amdgcn_mfma_f32_16x16x32_f16(ph,  vh, o1, 0,0,0);
    o2 = __builtin_amdgcn_mfma_f32_16x16x32_f16(ph,  vl, o2, 0,0,0);
    o2 = __builtin_amdgcn_mfma_f32_16x16x32_f16(plo, vh, o2, 0,0,0);
  }
  #pragma unroll
  for (int r = 0; r < 4; r++){
    int slot = q*4 + r;
    if (slot < 8)
      part[((long)(b*16 + c)*8 + slot)*66 + 2 + w*16 + l15] = o1[r] + o2[r] * LO_INV;
  }
}

// ---------------------------------------------------------------------------
// per-(b,slot) combine of 16 chunk partials + GRU + (LN+q | final outputs)
// ---------------------------------------------------------------------------
__global__ __launch_bounds__(64)
void k_combine(const float* __restrict__ part, float* __restrict__ slots,
               float* __restrict__ qws, float* __restrict__ mlws,
               const float* __restrict__ W_ih, const float* __restrict__ W_hh,
               const float* __restrict__ b_ih, const float* __restrict__ b_hh,
               const float* __restrict__ g_s, const float* __restrict__ b_s,
               const float* __restrict__ Wq, const float* __restrict__ Wval,
               const float* __restrict__ bval, float* __restrict__ out, int last)
{
  const int row = blockIdx.x;          // b*8 + slot
  const int d = threadIdx.x;
  const int b = row >> 3, kk = row & 7;
  __shared__ float upd_s[64], h_s[64], sn_s[64];

  const float* pp = part + ((long)(b*16)*8 + kk)*66;
  float m = NEG_BIG;
  #pragma unroll
  for (int c = 0; c < 16; c++) m = fmaxf(m, pp[c*528]);
  float lsum = 0.f, o = 0.f;
  #pragma unroll
  for (int c = 0; c < 16; c++){
    const float* pc = pp + c*528;
    float e = expf(pc[0] - m);
    lsum += pc[1] * e;
    o    += pc[2 + d] * e;
  }
  float upd = o / lsum;
  if (last && d == 0){ mlws[row*2] = m; mlws[row*2 + 1] = lsum; }

  float h = slots[row*64 + d];
  upd_s[d] = upd; h_s[d] = h;
  __syncthreads();

  float xr = b_ih[d], xz = b_ih[64 + d], xn = b_ih[128 + d];
  float hr = b_hh[d], hz = b_hh[64 + d], hn = b_hh[128 + d];
  for (int j = 0; j < 64; j++){
    float u = upd_s[j], hh = h_s[j];
    xr += u  * W_ih[j*192 + d];
    xz += u  * W_ih[j*192 + 64 + d];
    xn += u  * W_ih[j*192 + 128 + d];
    hr += hh * W_hh[j*192 + d];
    hz += hh * W_hh[j*192 + 64 + d];
    hn += hh * W_hh[j*192 + 128 + d];
  }
  float r = 1.f / (1.f + expf(-(xr + hr)));
  float z = 1.f / (1.f + expf(-(xz + hz)));
  float n = tanhf(xn + r * hn);
  float hnew = (1.f - z) * n + z * h;
  slots[row*64 + d] = hnew;

  if (!last){
    float s1 = wsum(hnew), s2 = wsum(hnew * hnew);
    float mean = s1 * (1.f/64.f);
    float rstd = rsqrtf(fmaxf(s2 * (1.f/64.f) - mean*mean, 0.f) + 1e-5f);
    float sn = (hnew - mean) * rstd * g_s[d] + b_s[d];
    sn_s[d] = sn;
    __syncthreads();
    float qd = 0.f;
    for (int j = 0; j < 64; j++) qd += sn_s[j] * Wq[j*64 + d];
    qws[row*64 + d] = qd;
  } else {
    out[row*64 + d] = hnew;
    float val = wsum(hnew * Wval[d]);
    if (d == 0)
      out[1064960 + row] = ((val + bval[0]) > 0.f) ? 1.f : 0.f;
  }
}

// initial slots broadcast + LN + q
__global__ __launch_bounds__(64)
void k_init(const float* __restrict__ emb, const float* __restrict__ g_s,
            const float* __restrict__ b_s, const float* __restrict__ Wq,
            float* __restrict__ slots, float* __restrict__ qws)
{
  const int row = blockIdx.x, d = threadIdx.x, kk = row & 7;
  __shared__ float sn_s[64];
  float x = emb[kk*64 + d];
  slots[row*64 + d] = x;
  float s1 = wsum(x), s2 = wsum(x * x);
  float mean = s1 * (1.f/64.f);
  float rstd = rsqrtf(fmaxf(s2 * (1.f/64.f) - mean*mean, 0.f) + 1e-5f);
  float sn = (x - mean) * rstd * g_s[d] + b_s[d];
  sn_s[d] = sn;
  __syncthreads();
  float qd = 0.f;
  for (int j = 0; j < 64; j++) qd += sn_s[j] * Wq[j*64 + d];
  qws[row*64 + d] = qd;
}

// final attn output from persisted scores + final (m,l)
__global__ __launch_bounds__(256)
void k_attn_out(const float* __restrict__ scores, const float* __restrict__ mlws,
                float* __restrict__ out)
{
  const int c = blockIdx.x, b = blockIdx.y, t = threadIdx.x;
  const int s = c*256 + t;
  #pragma unroll
  for (int k8 = 0; k8 < 8; k8++){
    int row = b*8 + k8;
    float m = mlws[row*2], lsum = mlws[row*2 + 1];
    float sc = scores[(long)row*4096 + s];
    out[16384 + (long)row*4096 + s] = expf(sc - m) / lsum;
  }
}

extern "C" void kernel_launch(void* const* d_in, const int* in_sizes, int n_in,
                              void* d_out, int out_size, void* d_ws, size_t ws_size,
                              hipStream_t stream)
{
  const float* inputs = (const float*)d_in[0];
  const int*   mask   = (const int*)  d_in[1];
  const float* emb    = (const float*)d_in[2];
  const float* Wq     = (const float*)d_in[3];
  const float* Wk     = (const float*)d_in[4];
  const float* Wv     = (const float*)d_in[5];
  const float* W_ih   = (const float*)d_in[6];
  const float* W_hh   = (const float*)d_in[7];
  const float* b_ih   = (const float*)d_in[8];
  const float* b_hh   = (const float*)d_in[9];
  const float* g_in   = (const float*)d_in[10];
  const float* b_in   = (const float*)d_in[11];
  const float* g_s    = (const float*)d_in[12];
  const float* b_s    = (const float*)d_in[13];
  const float* Wval   = (const float*)d_in[14];
  const float* bval   = (const float*)d_in[15];

  char* ws = (char*)d_ws;
  u32*   kws    = (u32*)  (ws);                         // 32 MB  [b][s][d] packed hi/lo
  u32*   vws    = (u32*)  (ws + (32ull<<20));           // 32 MB  [b][d][s] packed hi/lo
  float* scores = (float*)(ws + (64ull<<20));           //  4 MB  fp32 masked+scaled
  float* part   = (float*)(ws + (68ull<<20));           // ~1 MB  [b][c][slot][66]
  float* slots  = (float*)(ws + (70ull<<20));           // 64 KB
  float* qws    = (float*)(ws + (70ull<<20) + 65536);   // 64 KB
  float* mlws   = (float*)(ws + (70ull<<20) + 131072);  //  2 KB

  float* out = (float*)d_out;

  k_proj<<<2048, 256, 0, stream>>>(inputs, g_in, b_in, Wk, Wv, kws, vws);
  k_init<<<256, 64, 0, stream>>>(emb, g_s, b_s, Wq, slots, qws);

  for (int it = 0; it < 3; ++it){
    k_attn_part<<<dim3(16, 32), 256, 0, stream>>>(qws, kws, vws, mask, scores, part);
    k_combine<<<256, 64, 0, stream>>>(part, slots, qws, mlws,
                                      W_ih, W_hh, b_ih, b_hh, g_s, b_s,
                                      Wq, Wval, bval, out, it == 2);
  }
  k_attn_out<<<dim3(16, 32), 256, 0, stream>>>(scores, mlws, out);
}

// Round 5
// 322.243 us; speedup vs baseline: 1.0458x; 1.0458x over previous
//
#include <hip/hip_runtime.h>

typedef unsigned short u16;
typedef unsigned int   u32;
typedef _Float16 f16x8 __attribute__((ext_vector_type(8)));
typedef u16    u16x4 __attribute__((ext_vector_type(4)));
typedef u16    u16x8 __attribute__((ext_vector_type(8)));
typedef u32    u32x4 __attribute__((ext_vector_type(4)));
typedef float  f32x4 __attribute__((ext_vector_type(4)));

#define NEG_BIG (-3.4028234663852886e38f)
#define LO_SCALE 2048.0f
#define LO_INV   (1.0f/2048.0f)
#define LO_INV2  (1.0f/4194304.0f)

__device__ __forceinline__ void split2(float x, _Float16& h, _Float16& l){
  h = (_Float16)x;
  l = (_Float16)((x - (float)h) * LO_SCALE);
}
__device__ __forceinline__ u16 f2u(_Float16 h){ return __builtin_bit_cast(u16, h); }
__device__ __forceinline__ float wsum(float v){
  #pragma unroll
  for (int m = 32; m >= 1; m >>= 1) v += __shfl_xor(v, m, 64);
  return v;
}
__device__ __forceinline__ float wmax(float v){
  #pragma unroll
  for (int m = 32; m >= 1; m >>= 1) v = fmaxf(v, __shfl_xor(v, m, 64));
  return v;
}

// ---------------------------------------------------------------------------
// K-1: split [Wk|Wv] into MFMA-B-fragment-ordered f16 hi/lo planes.
// Bh/Bl index: ((ntile*8 + kt)*64 + lane)*8 + j ; n = ntile*16 + (lane&15),
// k = kt*32 + (lane>>4)*8 + j.
// ---------------------------------------------------------------------------
__global__ __launch_bounds__(256)
void k_prep(const float* __restrict__ Wk, const float* __restrict__ Wv,
            u16* __restrict__ Bh, u16* __restrict__ Bl)
{
  const int gid = blockIdx.x * 256 + threadIdx.x;   // 0..4095
  const int lane = gid & 63, kt = (gid >> 6) & 7, ntile = gid >> 9;
  const int q = lane >> 4, l15 = lane & 15;
  const int n = ntile * 16 + l15;
  u16x8 hh, ll;
  #pragma unroll
  for (int j = 0; j < 8; j++){
    int k = kt*32 + q*8 + j;
    float wv = (n < 64) ? Wk[k*64 + n] : Wv[k*64 + (n - 64)];
    _Float16 h, lo; split2(wv, h, lo);
    hh[j] = f2u(h); ll[j] = f2u(lo);
  }
  *(u16x8*)(Bh + (long)gid*8) = hh;
  *(u16x8*)(Bl + (long)gid*8) = ll;
}

// ---------------------------------------------------------------------------
// K0: LN(inputs); [k|v] = xn @ [Wk|Wv] via 4-term split-f16 MFMA (fp32-exact
// class). M=32 rows/block (grid 4096), hi/lo A-planes in LDS.
// Outputs: kh/kl [b][s][d] f16, vh/vl [b][d][s] f16.
// ---------------------------------------------------------------------------
__global__ __launch_bounds__(256, 3)
void k_proj(const float* __restrict__ in, const float* __restrict__ g,
            const float* __restrict__ bb,
            const u16* __restrict__ Bh, const u16* __restrict__ Bl,
            u16* __restrict__ kh, u16* __restrict__ kl,
            u16* __restrict__ vh, u16* __restrict__ vl)
{
  __shared__ __align__(16) u16 Ah[32 * 264];
  __shared__ __align__(16) u16 Al[32 * 264];
  const int t = threadIdx.x, w = t >> 6, l = t & 63, q = l >> 4, l15 = l & 15;
  const long base = (long)blockIdx.x * 32;

  f32x4 xv[8];
  const f32x4* in4 = (const f32x4*)in;
  #pragma unroll
  for (int i = 0; i < 8; i++) xv[i] = in4[(base + i*4 + w) * 64 + l];

  const f32x4 gv = ((const f32x4*)g)[l];
  const f32x4 bv = ((const f32x4*)bb)[l];

  #pragma unroll
  for (int i = 0; i < 8; i++){
    f32x4 x = xv[i];
    float s  = x.x + x.y + x.z + x.w;
    float ss = x.x*x.x + x.y*x.y + x.z*x.z + x.w*x.w;
    s = wsum(s); ss = wsum(ss);
    float mean = s * (1.f/256.f);
    float var  = fmaxf(ss * (1.f/256.f) - mean*mean, 0.f);
    float rstd = rsqrtf(var + 1e-5f);
    int row = i*4 + w;
    float y0 = (x.x - mean) * rstd * gv.x + bv.x;
    float y1 = (x.y - mean) * rstd * gv.y + bv.y;
    float y2 = (x.z - mean) * rstd * gv.z + bv.z;
    float y3 = (x.w - mean) * rstd * gv.w + bv.w;
    _Float16 h0,l0,h1,l1,h2,l2,h3,l3;
    split2(y0,h0,l0); split2(y1,h1,l1); split2(y2,h2,l2); split2(y3,h3,l3);
    u16x4 hv = { f2u(h0), f2u(h1), f2u(h2), f2u(h3) };
    u16x4 lv = { f2u(l0), f2u(l1), f2u(l2), f2u(l3) };
    *(u16x4*)&Ah[row*264 + l*4] = hv;
    *(u16x4*)&Al[row*264 + l*4] = lv;
  }
  __syncthreads();

  f32x4 a1[2][2] = {};   // hi*hi
  f32x4 a2[2][2] = {};   // hi*lo + lo*hi   (2^11 scale)
  f32x4 a3[2][2] = {};   // lo*lo           (2^22 scale)

  #pragma unroll
  for (int kt = 0; kt < 8; kt++){
    f16x8 bhv[2], blv[2];
    #pragma unroll
    for (int n2 = 0; n2 < 2; n2++){
      long idx = ((long)((w*2 + n2)*8 + kt)*64 + l)*8;
      bhv[n2] = __builtin_bit_cast(f16x8, *(const u32x4*)(Bh + idx));
      blv[n2] = __builtin_bit_cast(f16x8, *(const u32x4*)(Bl + idx));
    }
    f16x8 ahv[2], alv[2];
    #pragma unroll
    for (int mt = 0; mt < 2; mt++){
      int off = (mt*16 + l15)*264 + kt*32 + q*8;
      ahv[mt] = __builtin_bit_cast(f16x8, *(const u32x4*)&Ah[off]);
      alv[mt] = __builtin_bit_cast(f16x8, *(const u32x4*)&Al[off]);
    }
    #pragma unroll
    for (int mt = 0; mt < 2; mt++)
      #pragma unroll
      for (int n2 = 0; n2 < 2; n2++){
        a1[mt][n2] = __builtin_amdgcn_mfma_f32_16x16x32_f16(ahv[mt], bhv[n2], a1[mt][n2], 0,0,0);
        a2[mt][n2] = __builtin_amdgcn_mfma_f32_16x16x32_f16(ahv[mt], blv[n2], a2[mt][n2], 0,0,0);
        a2[mt][n2] = __builtin_amdgcn_mfma_f32_16x16x32_f16(alv[mt], bhv[n2], a2[mt][n2], 0,0,0);
        a3[mt][n2] = __builtin_amdgcn_mfma_f32_16x16x32_f16(alv[mt], blv[n2], a3[mt][n2], 0,0,0);
      }
  }
  __syncthreads();

  // stage C hi/lo planes (32 x 128, stride 264) for coalesced writes
  #pragma unroll
  for (int mt = 0; mt < 2; mt++)
    #pragma unroll
    for (int n2 = 0; n2 < 2; n2++)
      #pragma unroll
      for (int r = 0; r < 4; r++){
        int row = mt*16 + q*4 + r;
        int col = w*32 + n2*16 + l15;          // 0..63 k, 64..127 v
        float val = a1[mt][n2][r] + a2[mt][n2][r]*LO_INV + a3[mt][n2][r]*LO_INV2;
        _Float16 h, lo; split2(val, h, lo);
        Ah[row*264 + col] = f2u(h);
        Al[row*264 + col] = f2u(lo);
      }
  __syncthreads();

  const int b  = (int)(base >> 12);
  const int s0 = (int)(base & 4095);
  {
    int row = t >> 3, seg = t & 7;
    long o = ((long)b*4096 + s0 + row)*64 + seg*8;
    *(u16x8*)(kh + o) = *(const u16x8*)&Ah[row*264 + seg*8];
    *(u16x8*)(kl + o) = *(const u16x8*)&Al[row*264 + seg*8];
  }
  {
    int d = t >> 2, seg = t & 3;
    u16x8 hv, lv;
    #pragma unroll
    for (int j = 0; j < 8; j++){
      hv[j] = Ah[(seg*8 + j)*264 + 64 + d];
      lv[j] = Al[(seg*8 + j)*264 + 64 + d];
    }
    long o = ((long)b*64 + d)*4096 + s0 + seg*8;
    *(u16x8*)(vh + o) = hv;
    *(u16x8*)(vl + o) = lv;
  }
}

// ---------------------------------------------------------------------------
// per-(b, s-chunk of 256): scores via 4-term split-f16 MFMA, chunk softmax
// stats, PV partial via 4-term split-f16 MFMA. scores persisted on last iter.
// ---------------------------------------------------------------------------
__global__ __launch_bounds__(256)
void k_attn_part(const float* __restrict__ qws,
                 const u16* __restrict__ kh, const u16* __restrict__ kl,
                 const u16* __restrict__ vh, const u16* __restrict__ vl,
                 const int* __restrict__ mask,
                 float* __restrict__ scores, float* __restrict__ part, int last)
{
  __shared__ float pl[8 * 257];
  __shared__ __align__(16) u16 ph[16 * 264];
  __shared__ __align__(16) u16 plo[16 * 264];
  __shared__ float ml[8];
  const int c = blockIdx.x, b = blockIdx.y;
  const int t = threadIdx.x, w = t >> 6, l = t & 63, q = l >> 4, l15 = l & 15;

  // --- phase 1: scores = K_chunk(256x64) @ Q^T ; wave w -> s in [64w,64w+64)
  f16x8 qh[2], ql[2];
  #pragma unroll
  for (int kt = 0; kt < 2; kt++){
    #pragma unroll
    for (int j = 0; j < 8; j++){
      int d = kt*32 + q*8 + j;
      float qv = (l15 < 8) ? qws[b*512 + l15*64 + d] : 0.f;
      _Float16 h, lo; split2(qv, h, lo);
      qh[kt][j] = h; ql[kt][j] = lo;
    }
  }
  f32x4 s1[4] = {}, s2[4] = {}, s3[4] = {};
  #pragma unroll
  for (int kt = 0; kt < 2; kt++)
    #pragma unroll
    for (int mt = 0; mt < 4; mt++){
      long o = ((long)b*4096 + c*256 + w*64 + mt*16 + l15)*64 + kt*32 + q*8;
      f16x8 ah = __builtin_bit_cast(f16x8, *(const u32x4*)(kh + o));
      f16x8 al = __builtin_bit_cast(f16x8, *(const u32x4*)(kl + o));
      s1[mt] = __builtin_amdgcn_mfma_f32_16x16x32_f16(ah, qh[kt], s1[mt], 0,0,0);
      s2[mt] = __builtin_amdgcn_mfma_f32_16x16x32_f16(ah, ql[kt], s2[mt], 0,0,0);
      s2[mt] = __builtin_amdgcn_mfma_f32_16x16x32_f16(al, qh[kt], s2[mt], 0,0,0);
      s3[mt] = __builtin_amdgcn_mfma_f32_16x16x32_f16(al, ql[kt], s3[mt], 0,0,0);
    }
  #pragma unroll
  for (int mt = 0; mt < 4; mt++)
    #pragma unroll
    for (int r = 0; r < 4; r++)
      if (l15 < 8)
        pl[l15*257 + w*64 + mt*16 + q*4 + r] =
            s1[mt][r] + s2[mt][r]*LO_INV + s3[mt][r]*LO_INV2;
  __syncthreads();

  // --- phase 2: scale + mask; persist scores only on last iter
  const int s = c*256 + t;
  const int mk = mask[b*4096 + s];
  float sc[8];
  #pragma unroll
  for (int k8 = 0; k8 < 8; k8++){
    float v0 = pl[k8*257 + t] * 0.125f;
    sc[k8] = mk ? v0 : NEG_BIG;
    if (last) scores[((long)(b*8 + k8))*4096 + s] = sc[k8];
    pl[k8*257 + t] = sc[k8];
  }
  __syncthreads();

  // --- phase 3: chunk max per slot (wave w -> slots 2w, 2w+1)
  #pragma unroll
  for (int i = 0; i < 2; i++){
    int slot = w*2 + i;
    float m = fmaxf(fmaxf(pl[slot*257 + l],       pl[slot*257 + 64 + l]),
                    fmaxf(pl[slot*257 + 128 + l], pl[slot*257 + 192 + l]));
    m = wmax(m);
    if (l == 0) ml[slot] = m;
  }
  __syncthreads();

  // --- phase 4: p = exp(sc - m); fp32 in pl, f16 hi/lo planes for MFMA
  #pragma unroll
  for (int k8 = 0; k8 < 8; k8++){
    float p = mk ? expf(sc[k8] - ml[k8]) : 0.f;
    pl[k8*257 + t] = p;
    _Float16 h, lo; split2(p, h, lo);
    ph[k8*264 + t] = f2u(h);
    plo[k8*264 + t] = f2u(lo);
  }
  #pragma unroll
  for (int k8 = 8; k8 < 16; k8++){ ph[k8*264 + t] = 0; plo[k8*264 + t] = 0; }
  __syncthreads();

  // --- phase 5: chunk exp-sums -> (m, l) partials
  #pragma unroll
  for (int i = 0; i < 2; i++){
    int slot = w*2 + i;
    float sm = pl[slot*257 + l] + pl[slot*257 + 64 + l]
             + pl[slot*257 + 128 + l] + pl[slot*257 + 192 + l];
    sm = wsum(sm);
    if (l == 0){
      float* pp = part + ((long)(b*16 + c)*8 + slot)*66;
      pp[0] = ml[slot]; pp[1] = sm;
    }
  }

  // --- phase 6: o_partial = P(16pad x 256) @ V(256 x 64); wave w -> d-tile w
  f32x4 o1 = {}, o2 = {}, o3 = {};
  #pragma unroll
  for (int kt = 0; kt < 8; kt++){
    int poff = l15*264 + kt*32 + q*8;
    f16x8 pf = __builtin_bit_cast(f16x8, *(const u32x4*)&ph[poff]);
    f16x8 pg = __builtin_bit_cast(f16x8, *(const u32x4*)&plo[poff]);
    long voff = ((long)b*64 + w*16 + l15)*4096 + c*256 + kt*32 + q*8;
    f16x8 vhf = __builtin_bit_cast(f16x8, *(const u32x4*)(vh + voff));
    f16x8 vlf = __builtin_bit_cast(f16x8, *(const u32x4*)(vl + voff));
    o1 = __builtin_amdgcn_mfma_f32_16x16x32_f16(pf, vhf, o1, 0,0,0);
    o2 = __builtin_amdgcn_mfma_f32_16x16x32_f16(pf, vlf, o2, 0,0,0);
    o2 = __builtin_amdgcn_mfma_f32_16x16x32_f16(pg, vhf, o2, 0,0,0);
    o3 = __builtin_amdgcn_mfma_f32_16x16x32_f16(pg, vlf, o3, 0,0,0);
  }
  #pragma unroll
  for (int r = 0; r < 4; r++){
    int slot = q*4 + r;
    if (slot < 8)
      part[((long)(b*16 + c)*8 + slot)*66 + 2 + w*16 + l15] =
          o1[r] + o2[r]*LO_INV + o3[r]*LO_INV2;
  }
}

// ---------------------------------------------------------------------------
// per-row combine of 16 chunk partials + GRU + (LN+q | final outputs).
// 256 threads: d = t&63, jg = t>>6 splits 64-deep loops 4-way.
// All __syncthreads() are workgroup-uniform.
// ---------------------------------------------------------------------------
__global__ __launch_bounds__(256)
void k_combine(const float* __restrict__ part, float* __restrict__ slots,
               float* __restrict__ qws, float* __restrict__ mlws,
               const float* __restrict__ W_ih, const float* __restrict__ W_hh,
               const float* __restrict__ b_ih, const float* __restrict__ b_hh,
               const float* __restrict__ g_s, const float* __restrict__ b_s,
               const float* __restrict__ Wq, const float* __restrict__ Wval,
               const float* __restrict__ bval, float* __restrict__ out, int last)
{
  const int row = blockIdx.x;          // b*8 + slot
  const int t = threadIdx.x;
  const int d = t & 63, jg = t >> 6;
  const int b = row >> 3, kk = row & 7;
  __shared__ float redO[4][64], redL[4][64];
  __shared__ float redG[4][6][64];
  __shared__ float upd_s[64], h_s[64], hn_s[64], sn_s[64];

  const float* pp = part + ((long)(b*16)*8 + kk)*66;
  float m = NEG_BIG;
  #pragma unroll
  for (int c = 0; c < 16; c++) m = fmaxf(m, pp[c*528]);
  float lsum = 0.f, o = 0.f;
  #pragma unroll
  for (int ci = 0; ci < 4; ci++){
    const float* pc = pp + (jg*4 + ci)*528;
    float e = expf(pc[0] - m);
    lsum += pc[1] * e;
    o    += pc[2 + d] * e;
  }
  redO[jg][d] = o; redL[jg][d] = lsum;
  __syncthreads();
  if (jg == 0){
    float oo = redO[0][d] + redO[1][d] + redO[2][d] + redO[3][d];
    float ll = redL[0][d] + redL[1][d] + redL[2][d] + redL[3][d];
    upd_s[d] = oo / ll;
    h_s[d] = slots[row*64 + d];
    if (last && d == 0){ mlws[row*2] = m; mlws[row*2 + 1] = ll; }
  }
  __syncthreads();

  float a0=0,a1=0,a2=0,a3=0,a4=0,a5=0;
  #pragma unroll
  for (int ji = 0; ji < 16; ji++){
    int j = jg*16 + ji;
    float u = upd_s[j], hh = h_s[j];
    a0 += u  * W_ih[j*192 + d];
    a1 += u  * W_ih[j*192 + 64 + d];
    a2 += u  * W_ih[j*192 + 128 + d];
    a3 += hh * W_hh[j*192 + d];
    a4 += hh * W_hh[j*192 + 64 + d];
    a5 += hh * W_hh[j*192 + 128 + d];
  }
  redG[jg][0][d]=a0; redG[jg][1][d]=a1; redG[jg][2][d]=a2;
  redG[jg][3][d]=a3; redG[jg][4][d]=a4; redG[jg][5][d]=a5;
  __syncthreads();

  if (jg == 0){
    float xr = b_ih[d]       + redG[0][0][d]+redG[1][0][d]+redG[2][0][d]+redG[3][0][d];
    float xz = b_ih[64 + d]  + redG[0][1][d]+redG[1][1][d]+redG[2][1][d]+redG[3][1][d];
    float xn = b_ih[128 + d] + redG[0][2][d]+redG[1][2][d]+redG[2][2][d]+redG[3][2][d];
    float hr = b_hh[d]       + redG[0][3][d]+redG[1][3][d]+redG[2][3][d]+redG[3][3][d];
    float hz = b_hh[64 + d]  + redG[0][4][d]+redG[1][4][d]+redG[2][4][d]+redG[3][4][d];
    float hn = b_hh[128 + d] + redG[0][5][d]+redG[1][5][d]+redG[2][5][d]+redG[3][5][d];
    float r = 1.f / (1.f + expf(-(xr + hr)));
    float z = 1.f / (1.f + expf(-(xz + hz)));
    float n = tanhf(xn + r * hn);
    float h = h_s[d];
    float hnew = (1.f - z) * n + z * h;
    slots[row*64 + d] = hnew;
    hn_s[d] = hnew;
  }
  __syncthreads();

  if (!last){
    float hv = hn_s[d];                       // same value in all 4 waves
    float s1 = wsum(hv), s2 = wsum(hv * hv);
    float mean = s1 * (1.f/64.f);
    float rstd = rsqrtf(fmaxf(s2 * (1.f/64.f) - mean*mean, 0.f) + 1e-5f);
    float sn = (hv - mean) * rstd * g_s[d] + b_s[d];
    if (jg == 0) sn_s[d] = sn;
    __syncthreads();
    float qd = 0.f;
    #pragma unroll
    for (int ji = 0; ji < 16; ji++){
      int j = jg*16 + ji;
      qd += sn_s[j] * Wq[j*64 + d];
    }
    redO[jg][d] = qd;
    __syncthreads();
    if (jg == 0)
      qws[row*64 + d] = redO[0][d] + redO[1][d] + redO[2][d] + redO[3][d];
  } else {
    if (jg == 0){
      float hv = hn_s[d];
      out[row*64 + d] = hv;
      float val = wsum(hv * Wval[d]);
      if (d == 0)
        out[1064960 + row] = ((val + bval[0]) > 0.f) ? 1.f : 0.f;
    }
  }
}

// initial slots broadcast + LN + q
__global__ __launch_bounds__(64)
void k_init(const float* __restrict__ emb, const float* __restrict__ g_s,
            const float* __restrict__ b_s, const float* __restrict__ Wq,
            float* __restrict__ slots, float* __restrict__ qws)
{
  const int row = blockIdx.x, d = threadIdx.x, kk = row & 7;
  __shared__ float sn_s[64];
  float x = emb[kk*64 + d];
  slots[row*64 + d] = x;
  float s1 = wsum(x), s2 = wsum(x * x);
  float mean = s1 * (1.f/64.f);
  float rstd = rsqrtf(fmaxf(s2 * (1.f/64.f) - mean*mean, 0.f) + 1e-5f);
  float sn = (x - mean) * rstd * g_s[d] + b_s[d];
  sn_s[d] = sn;
  __syncthreads();
  float qd = 0.f;
  for (int j = 0; j < 64; j++) qd += sn_s[j] * Wq[j*64 + d];
  qws[row*64 + d] = qd;
}

// final attn output from persisted scores + final (m,l)
__global__ __launch_bounds__(256)
void k_attn_out(const float* __restrict__ scores, const float* __restrict__ mlws,
                float* __restrict__ out)
{
  const int c = blockIdx.x, b = blockIdx.y, t = threadIdx.x;
  const int s = c*256 + t;
  #pragma unroll
  for (int k8 = 0; k8 < 8; k8++){
    int row = b*8 + k8;
    float m = mlws[row*2], lsum = mlws[row*2 + 1];
    float sc = scores[(long)row*4096 + s];
    out[16384 + (long)row*4096 + s] = expf(sc - m) / lsum;
  }
}

extern "C" void kernel_launch(void* const* d_in, const int* in_sizes, int n_in,
                              void* d_out, int out_size, void* d_ws, size_t ws_size,
                              hipStream_t stream)
{
  const float* inputs = (const float*)d_in[0];
  const int*   mask   = (const int*)  d_in[1];
  const float* emb    = (const float*)d_in[2];
  const float* Wq     = (const float*)d_in[3];
  const float* Wk     = (const float*)d_in[4];
  const float* Wv     = (const float*)d_in[5];
  const float* W_ih   = (const float*)d_in[6];
  const float* W_hh   = (const float*)d_in[7];
  const float* b_ih   = (const float*)d_in[8];
  const float* b_hh   = (const float*)d_in[9];
  const float* g_in   = (const float*)d_in[10];
  const float* b_in   = (const float*)d_in[11];
  const float* g_s    = (const float*)d_in[12];
  const float* b_s    = (const float*)d_in[13];
  const float* Wval   = (const float*)d_in[14];
  const float* bval   = (const float*)d_in[15];

  char* ws = (char*)d_ws;
  const unsigned long MiB = 1ull << 20;
  u16*   kh     = (u16*)  (ws);                          // 16 MiB each plane
  u16*   kl     = (u16*)  (ws + 16*MiB);
  u16*   vh     = (u16*)  (ws + 32*MiB);
  u16*   vl     = (u16*)  (ws + 48*MiB);
  u16*   Bh     = (u16*)  (ws + 64*MiB);                 // 64 KiB
  u16*   Bl     = (u16*)  (ws + 64*MiB + 65536);         // 64 KiB
  float* scores = (float*)(ws + 64*MiB + 131072);        // 4 MiB
  float* part   = (float*)(ws + 68*MiB + 131072);        // ~1.06 MiB
  float* slots  = (float*)(ws + 69*MiB + 131072 + 0x110000);
  float* qws    = (float*)(ws + 69*MiB + 131072 + 0x110000 + 65536);
  float* mlws   = (float*)(ws + 69*MiB + 131072 + 0x110000 + 131072);

  float* out = (float*)d_out;

  k_prep<<<16, 256, 0, stream>>>(Wk, Wv, Bh, Bl);
  k_proj<<<4096, 256, 0, stream>>>(inputs, g_in, b_in, Bh, Bl, kh, kl, vh, vl);
  k_init<<<256, 64, 0, stream>>>(emb, g_s, b_s, Wq, slots, qws);

  for (int it = 0; it < 3; ++it){
    k_attn_part<<<dim3(16, 32), 256, 0, stream>>>(qws, kh, kl, vh, vl, mask,
                                                  scores, part, it == 2);
    k_combine<<<256, 256, 0, stream>>>(part, slots, qws, mlws,
                                       W_ih, W_hh, b_ih, b_hh, g_s, b_s,
                                       Wq, Wval, bval, out, it == 2);
  }
  k_attn_out<<<dim3(16, 32), 256, 0, stream>>>(scores, mlws, out);
}